// Round 1
// baseline (2020.871 us; speedup 1.0000x reference)
//
#include <hip/hip_runtime.h>

typedef unsigned short u16;
typedef __attribute__((ext_vector_type(8))) short short8;
typedef __attribute__((ext_vector_type(4))) float f32x4;
typedef __attribute__((ext_vector_type(4))) unsigned short u16x4;

__device__ __forceinline__ float bf2f(u16 u){
  union { unsigned int i; float f; } x; x.i = ((unsigned int)u) << 16; return x.f;
}
__device__ __forceinline__ u16 f2bf(float f){
  union { float f; unsigned int i; } x; x.f = f;
  return (u16)((x.i + 0x7fffu + ((x.i >> 16) & 1u)) >> 16);
}
__device__ __forceinline__ void async16(const void* g, void* s){
  __builtin_amdgcn_global_load_lds((const __attribute__((address_space(1))) void*)g,
                                   (__attribute__((address_space(3))) void*)s, 16, 0, 0);
}

// ---------------- elementwise split kernels ----------------
__global__ __launch_bounds__(256) void k_split(const float* __restrict__ s,
                                               u16* __restrict__ dH, u16* __restrict__ dL){
  long i = ((long)blockIdx.x * 256 + threadIdx.x) * 4;
  f32x4 v = *(const f32x4*)(s + i);
  u16x4 hh, ll;
  #pragma unroll
  for (int j=0;j<4;j++){ u16 h = f2bf(v[j]); hh[j]=h; ll[j]=f2bf(v[j]-bf2f(h)); }
  *(u16x4*)(dH+i) = hh; *(u16x4*)(dL+i) = ll;
}

__global__ __launch_bounds__(256) void k_addpe(const float* __restrict__ x, const float* __restrict__ pe,
                                               u16* __restrict__ dH, u16* __restrict__ dL){
  long i = ((long)blockIdx.x * 256 + threadIdx.x) * 4;
  f32x4 xv = *(const f32x4*)(x + i);
  f32x4 pv = *(const f32x4*)(pe + (i & 1048575));  // i % (L*D), pe broadcast over batch
  u16x4 hh, ll;
  #pragma unroll
  for (int j=0;j<4;j++){ float v = xv[j]+pv[j]; u16 h = f2bf(v); hh[j]=h; ll[j]=f2bf(v-bf2f(h)); }
  *(u16x4*)(dH+i) = hh; *(u16x4*)(dL+i) = ll;
}

// ---------------- 64x64 tiled transpose (hi & lo), (B,L,D)->(B,D,L) ----------------
__global__ __launch_bounds__(256) void k_transpose(const u16* __restrict__ iH, const u16* __restrict__ iL,
                                                   u16* __restrict__ oH, u16* __restrict__ oL){
  __shared__ u16 tile[64][68];   // row stride 136B: 8B-aligned, column reads ~2-way conflicts
  const long b = blockIdx.z;
  const int d0 = blockIdx.x * 64, l0 = blockIdx.y * 64;
  const long ibase = b * 1048576l;
  const int t = threadIdx.x;
  const int cr = t >> 4;         // 0..15
  const int cc = (t & 15) * 4;   // 0..60
  #pragma unroll
  for (int pass=0; pass<2; pass++){
    const u16* src = pass ? iL : iH;
    u16* dst = pass ? oL : oH;
    if (pass) __syncthreads();
    #pragma unroll
    for (int rr=0; rr<4; rr++){
      int row = cr + rr*16;
      u16x4 v = *(const u16x4*)(src + ibase + (long)(l0+row)*1024 + d0 + cc);
      *(u16x4*)&tile[row][cc] = v;
    }
    __syncthreads();
    #pragma unroll
    for (int rr=0; rr<4; rr++){
      int drow = cr + rr*16;
      u16x4 y;
      y[0] = tile[cc+0][drow];
      y[1] = tile[cc+1][drow];
      y[2] = tile[cc+2][drow];
      y[3] = tile[cc+3][drow];
      *(u16x4*)(dst + ibase + (long)(d0+drow)*1024 + l0 + cc) = y;
    }
  }
}

// ---------------- split-bf16 (3-MFMA) 128x128 GEMM, C = A * B^T ----------------
// A: M x K hi/lo (K-contig), B: N x K hi/lo (K-contig).
// MODE 0: C_f32 = acc*scale                    (QK -> scores)
// MODE 1: split-store acc -> cH/cL             (PV -> ctx)
// MODE 2: relu(acc+bias) -> split cH/cL        (FFN1 -> y1)
// MODE 3: acc+bias+res(hi+lo) -> C_f32         (FFN2 -> pre-LN)
template<int MODE>
__global__ __launch_bounds__(256) void gemm3(
    const u16* __restrict__ aH, const u16* __restrict__ aL,
    const u16* __restrict__ bH, const u16* __restrict__ bL,
    int K, int lda, int ldb, int ldc,
    long strideA, long strideB, long strideC,
    float scale, const float* __restrict__ bias,
    const u16* __restrict__ resH, const u16* __restrict__ resL,
    float* __restrict__ cF, u16* __restrict__ cH, u16* __restrict__ cL)
{
  __shared__ __align__(16) u16 sm[16384];   // AH | AL | BH | BL, each 128x32 bf16 (4096 u16)
  const int t = threadIdx.x;
  const int w = t >> 6;
  const int lane = t & 63;
  const long bz = blockIdx.z;
  const int m0 = blockIdx.y << 7, n0 = blockIdx.x << 7;
  aH += bz * strideA; aL += bz * strideA;
  bH += bz * strideB; bL += bz * strideB;

  // staging: LDS unit u (16B) = i*256 + t; physical layout row-major [128 rows][4 units].
  // XOR swizzle: physical slot s' holds logical k-slot  s' ^ ((row>>1)&3)  -> conflict-free ds_read_b128.
  const int rA0 = t >> 2;
  const int rA1 = 64 + rA0;
  const int s0 = (t & 3) ^ ((rA0 >> 1) & 3);
  const int s1 = (t & 3) ^ ((rA1 >> 1) & 3);
  const u16* gA0H = aH + (long)(m0 + rA0) * lda + s0 * 8;
  const u16* gA1H = aH + (long)(m0 + rA1) * lda + s1 * 8;
  const u16* gA0L = aL + (long)(m0 + rA0) * lda + s0 * 8;
  const u16* gA1L = aL + (long)(m0 + rA1) * lda + s1 * 8;
  const u16* gB0H = bH + (long)(n0 + rA0) * ldb + s0 * 8;
  const u16* gB1H = bH + (long)(n0 + rA1) * ldb + s1 * 8;
  const u16* gB0L = bL + (long)(n0 + rA0) * ldb + s0 * 8;
  const u16* gB1L = bL + (long)(n0 + rA1) * ldb + s1 * 8;
  u16* ldsW = sm + (w << 9);   // wave-uniform base (w*512 u16)

  f32x4 acc[4][4];
  #pragma unroll
  for (int i=0;i<4;i++)
    #pragma unroll
    for (int j=0;j<4;j++) acc[i][j] = (f32x4){0.f,0.f,0.f,0.f};

  const int fr = lane & 15, fs = lane >> 4;
  int offA[4], offB[4];
  #pragma unroll
  for (int i=0;i<4;i++){
    int ra = (w >> 1)*64 + i*16 + fr;
    offA[i] = ra*32 + (fs ^ ((ra>>1)&3))*8;
    int rb = (w & 1)*64 + i*16 + fr;
    offB[i] = rb*32 + (fs ^ ((rb>>1)&3))*8;
  }

  for (int k0 = 0; k0 < K; k0 += 32){
    async16(gA0H + k0, ldsW + 0);
    async16(gA1H + k0, ldsW + 2048);
    async16(gA0L + k0, ldsW + 4096);
    async16(gA1L + k0, ldsW + 6144);
    async16(gB0H + k0, ldsW + 8192);
    async16(gB1H + k0, ldsW + 10240);
    async16(gB0L + k0, ldsW + 12288);
    async16(gB1L + k0, ldsW + 14336);
    __syncthreads();
    short8 ah[4], al[4];
    #pragma unroll
    for (int i=0;i<4;i++){
      ah[i] = *(const short8*)(sm + offA[i]);
      al[i] = *(const short8*)(sm + 4096 + offA[i]);
    }
    #pragma unroll
    for (int j=0;j<4;j++){
      short8 bh = *(const short8*)(sm + 8192  + offB[j]);
      short8 bl = *(const short8*)(sm + 12288 + offB[j]);
      #pragma unroll
      for (int i=0;i<4;i++){
        acc[i][j] = __builtin_amdgcn_mfma_f32_16x16x32_bf16(ah[i], bh, acc[i][j], 0,0,0);
        acc[i][j] = __builtin_amdgcn_mfma_f32_16x16x32_bf16(ah[i], bl, acc[i][j], 0,0,0);
        acc[i][j] = __builtin_amdgcn_mfma_f32_16x16x32_bf16(al[i], bh, acc[i][j], 0,0,0);
      }
    }
    __syncthreads();
  }

  const long cBase = bz * strideC;
  const int colb = n0 + (w & 1)*64 + fr;
  const int rowb = m0 + (w >> 1)*64 + fs*4;
  #pragma unroll
  for (int j=0;j<4;j++){
    const int c = colb + j*16;
    float bv = 0.f;
    if constexpr (MODE == 2 || MODE == 3) bv = bias[c];
    #pragma unroll
    for (int i=0;i<4;i++){
      #pragma unroll
      for (int q=0;q<4;q++){
        const int r = rowb + i*16 + q;
        const long idx = cBase + (long)r*ldc + c;
        float v = acc[i][j][q];
        if constexpr (MODE == 0){
          cF[idx] = v * scale;
        } else if constexpr (MODE == 1){
          u16 h = f2bf(v); cH[idx]=h; cL[idx]=f2bf(v - bf2f(h));
        } else if constexpr (MODE == 2){
          v = fmaxf(v + bv, 0.f);
          u16 h = f2bf(v); cH[idx]=h; cL[idx]=f2bf(v - bf2f(h));
        } else {
          v += bv + bf2f(resH[idx]) + bf2f(resL[idx]);
          cF[idx] = v;
        }
      }
    }
  }
}

// ---------------- row softmax over 1024, writes probs fp32 (in place, in d_out) + bf16 hi/lo ----------------
__global__ __launch_bounds__(256) void k_softmax(float* __restrict__ p,
                                                 u16* __restrict__ pH, u16* __restrict__ pL){
  const long row = blockIdx.x;
  float* pr = p + row * 1024;
  const int t = threadIdx.x, w = t >> 6, lane = t & 63;
  __shared__ float rA[4], rB[4];
  f32x4 v = *(const f32x4*)(pr + t*4);
  float m = fmaxf(fmaxf(v[0],v[1]), fmaxf(v[2],v[3]));
  #pragma unroll
  for (int off=32; off; off>>=1) m = fmaxf(m, __shfl_xor(m, off));
  if (lane==0) rA[w] = m;
  __syncthreads();
  m = fmaxf(fmaxf(rA[0],rA[1]), fmaxf(rA[2],rA[3]));
  float e[4]; float s = 0.f;
  #pragma unroll
  for (int j=0;j<4;j++){ e[j] = expf(v[j]-m); s += e[j]; }
  #pragma unroll
  for (int off=32; off; off>>=1) s += __shfl_xor(s, off);
  if (lane==0) rB[w] = s;
  __syncthreads();
  s = rB[0]+rB[1]+rB[2]+rB[3];
  const float inv = 1.0f / s;
  f32x4 o; u16x4 hh, ll;
  #pragma unroll
  for (int j=0;j<4;j++){
    float pv = e[j]*inv; o[j] = pv;
    u16 h = f2bf(pv); hh[j]=h; ll[j]=f2bf(pv - bf2f(h));
  }
  *(f32x4*)(pr + t*4) = o;
  *(u16x4*)(pH + row*1024 + t*4) = hh;
  *(u16x4*)(pL + row*1024 + t*4) = ll;
}

// ---------------- layernorm over 1024, writes h hi/lo ----------------
__global__ __launch_bounds__(256) void k_ln(const float* __restrict__ r,
                                            const float* __restrict__ g, const float* __restrict__ b,
                                            u16* __restrict__ hH, u16* __restrict__ hL){
  const long row = blockIdx.x;
  const float* rr = r + row * 1024;
  const int t = threadIdx.x, w = t >> 6, lane = t & 63;
  __shared__ float rA[4], rB[4];
  f32x4 v = *(const f32x4*)(rr + t*4);
  float s = v[0]+v[1]+v[2]+v[3];
  #pragma unroll
  for (int off=32; off; off>>=1) s += __shfl_xor(s, off);
  if (lane==0) rA[w] = s;
  __syncthreads();
  const float mu = (rA[0]+rA[1]+rA[2]+rA[3]) * (1.0f/1024.0f);
  float sq = 0.f;
  #pragma unroll
  for (int j=0;j<4;j++){ float d = v[j]-mu; sq += d*d; }
  #pragma unroll
  for (int off=32; off; off>>=1) sq += __shfl_xor(sq, off);
  if (lane==0) rB[w] = sq;
  __syncthreads();
  const float var = (rB[0]+rB[1]+rB[2]+rB[3]) * (1.0f/1024.0f);
  const float inv = rsqrtf(var + 1e-5f);
  u16x4 hh, ll;
  #pragma unroll
  for (int j=0;j<4;j++){
    int d = t*4+j;
    float hv = (v[j]-mu)*inv*g[d] + b[d];
    u16 h = f2bf(hv); hh[j]=h; ll[j]=f2bf(hv - bf2f(h));
  }
  *(u16x4*)(hH + row*1024 + t*4) = hh;
  *(u16x4*)(hL + row*1024 + t*4) = ll;
}

// ---------------- final head ----------------
__global__ __launch_bounds__(256) void k_final1(const u16* __restrict__ hH, const u16* __restrict__ hL,
                                                const float* __restrict__ fw, const float* __restrict__ fb,
                                                float* __restrict__ z){
  const int row = blockIdx.x*4 + (threadIdx.x>>6);
  const int lane = threadIdx.x & 63;
  const long base = (long)row * 1024;
  const int d0 = lane * 16;
  float s = 0.f;
  #pragma unroll
  for (int j=0;j<16;j++){
    int d = d0 + j;
    s += (bf2f(hH[base+d]) + bf2f(hL[base+d])) * fw[d];
  }
  #pragma unroll
  for (int off=32; off; off>>=1) s += __shfl_xor(s, off);
  if (lane==0) z[row] = s + fb[0];
}

__global__ __launch_bounds__(256) void k_final2(const float* __restrict__ z,
                                                const float* __restrict__ fw, const float* __restrict__ fb,
                                                float* __restrict__ out){
  const int idx = blockIdx.x*4 + (threadIdx.x>>6);   // 0..383 = b*24+o
  const int lane = threadIdx.x & 63;
  const int b = idx / 24, o = idx % 24;
  float s = 0.f;
  #pragma unroll
  for (int j=0;j<16;j++){
    int li = lane + j*64;
    s += z[b*1024 + li] * fw[o*1024 + li];
  }
  #pragma unroll
  for (int off=32; off; off>>=1) s += __shfl_xor(s, off);
  if (lane==0) out[idx] = s + fb[o];
}

// ---------------- launch ----------------
extern "C" void kernel_launch(void* const* d_in, const int* in_sizes, int n_in,
                              void* d_out, int out_size, void* d_ws, size_t ws_size,
                              hipStream_t stream){
  const float* x   = (const float*)d_in[0];
  const float* pe  = (const float*)d_in[1];
  const float* w1  = (const float*)d_in[2];
  const float* b1  = (const float*)d_in[3];
  const float* w2  = (const float*)d_in[4];
  const float* b2  = (const float*)d_in[5];
  const float* lng = (const float*)d_in[6];
  const float* lnb = (const float*)d_in[7];
  const float* fcw = (const float*)d_in[8];
  const float* fcb = (const float*)d_in[9];
  const float* fw  = (const float*)d_in[10];
  const float* fb  = (const float*)d_in[11];
  float* out  = (float*)d_out;
  float* attn = out + 384;                 // (3,16,1024,1024) fp32

  char* ws = (char*)d_ws;
  const long E  = 16l*1024*1024;           // elems in a (B,L,D) tensor
  const long BB = E*2;                     // bf16 buffer bytes (32MB)
  u16* hH = (u16*)(ws + 0*BB);
  u16* hL = (u16*)(ws + 1*BB);
  u16* tH = (u16*)(ws + 2*BB);             // h^T hi
  u16* tL = (u16*)(ws + 3*BB);             // h^T lo
  u16* cH = (u16*)(ws + 4*BB);             // ctx hi
  u16* cL = (u16*)(ws + 5*BB);             // ctx lo
  u16* pH = (u16*)(ws + 6*BB);             // probs hi (reused as y1 hi)
  u16* pL = (u16*)(ws + 7*BB);             // probs lo (reused as y1 lo)
  float* rf = (float*)(ws + 2*BB);         // pre-LN f32: ALIASES tH/tL (dead there, rewritten after LN)
  u16* w1H = (u16*)(ws + 8*BB);
  u16* w1L = w1H + 3l*1024*1024;
  u16* w2H = w1L + 3l*1024*1024;
  u16* w2L = w2H + 3l*1024*1024;
  float* z = (float*)(w2L + 3l*1024*1024); // (B,L) = 64KB

  const long M1 = 1024l*1024;

  k_split<<<3072, 256, 0, stream>>>(w1, w1H, w1L);
  k_split<<<3072, 256, 0, stream>>>(w2, w2H, w2L);
  k_addpe<<<16384, 256, 0, stream>>>(x, pe, hH, hL);
  k_transpose<<<dim3(16,16,16), 256, 0, stream>>>(hH, hL, tH, tL);

  for (int l = 0; l < 3; l++){
    float* sc = attn + (long)l*16*M1;
    // scores = h h^T / 32  -> d_out
    gemm3<0><<<dim3(8,8,16), 256, 0, stream>>>(hH,hL, hH,hL, 1024,1024,1024,1024,
        M1,M1,M1, 0.03125f, nullptr, nullptr,nullptr, sc, nullptr,nullptr);
    // softmax in place + bf16 hi/lo probs
    k_softmax<<<16384, 256, 0, stream>>>(sc, pH, pL);
    // ctx = P h   (B = h^T, K-contig)
    gemm3<1><<<dim3(8,8,16), 256, 0, stream>>>(pH,pL, tH,tL, 1024,1024,1024,1024,
        M1,M1,M1, 1.f, nullptr, nullptr,nullptr, nullptr, cH,cL);
    // y1 = relu(ctx w1^T + b1)
    gemm3<2><<<dim3(8,128,1), 256, 0, stream>>>(cH,cL, w1H+l*M1, w1L+l*M1, 1024,1024,1024,1024,
        0,0,0, 1.f, b1+l*1024, nullptr,nullptr, nullptr, pH,pL);
    // rf = y1 w2^T + b2 + ctx
    gemm3<3><<<dim3(8,128,1), 256, 0, stream>>>(pH,pL, w2H+l*M1, w2L+l*M1, 1024,1024,1024,1024,
        0,0,0, 1.f, b2+l*1024, cH,cL, rf, nullptr,nullptr);
    // h = LN(rf)*g + b  -> hi/lo
    k_ln<<<16384, 256, 0, stream>>>(rf, lng+l*1024, lnb+l*1024, hH, hL);
    if (l < 2) k_transpose<<<dim3(16,16,16), 256, 0, stream>>>(hH, hL, tH, tL);
  }

  k_final1<<<4096, 256, 0, stream>>>(hH, hL, fcw, fcb, z);
  k_final2<<<96, 256, 0, stream>>>(z, fw, fb, out);
}

// Round 2
// 881.598 us; speedup vs baseline: 2.2923x; 2.2923x over previous
//
#include <hip/hip_runtime.h>

typedef unsigned short u16;
typedef __attribute__((ext_vector_type(8))) short short8;
typedef __attribute__((ext_vector_type(4))) float f32x4;
typedef __attribute__((ext_vector_type(4))) unsigned short u16x4;

__device__ __forceinline__ float bf2f(u16 u){
  union { unsigned int i; float f; } x; x.i = ((unsigned int)u) << 16; return x.f;
}
__device__ __forceinline__ u16 f2bf(float f){
  union { float f; unsigned int i; } x; x.f = f;
  return (u16)((x.i + 0x7fffu + ((x.i >> 16) & 1u)) >> 16);
}
__device__ __forceinline__ void async16(const void* g, void* s){
  __builtin_amdgcn_global_load_lds((const __attribute__((address_space(1))) void*)g,
                                   (__attribute__((address_space(3))) void*)s, 16, 0, 0);
}

// ---------------- elementwise bf16-cast kernels ----------------
__global__ __launch_bounds__(256) void k_split(const float* __restrict__ s, u16* __restrict__ d){
  long i = ((long)blockIdx.x * 256 + threadIdx.x) * 4;
  f32x4 v = *(const f32x4*)(s + i);
  u16x4 hh;
  #pragma unroll
  for (int j=0;j<4;j++) hh[j] = f2bf(v[j]);
  *(u16x4*)(d+i) = hh;
}

__global__ __launch_bounds__(256) void k_addpe(const float* __restrict__ x, const float* __restrict__ pe,
                                               u16* __restrict__ d){
  long i = ((long)blockIdx.x * 256 + threadIdx.x) * 4;
  f32x4 xv = *(const f32x4*)(x + i);
  f32x4 pv = *(const f32x4*)(pe + (i & 1048575));  // i % (L*D), pe broadcast over batch
  u16x4 hh;
  #pragma unroll
  for (int j=0;j<4;j++) hh[j] = f2bf(xv[j]+pv[j]);
  *(u16x4*)(d+i) = hh;
}

// ---------------- 64x64 tiled transpose, (B,L,D)->(B,D,L) ----------------
__global__ __launch_bounds__(256) void k_transpose(const u16* __restrict__ in, u16* __restrict__ outp){
  __shared__ u16 tile[64][68];
  const long b = blockIdx.z;
  const int d0 = blockIdx.x * 64, l0 = blockIdx.y * 64;
  const long ibase = b * 1048576l;
  const int t = threadIdx.x;
  const int cr = t >> 4;         // 0..15
  const int cc = (t & 15) * 4;   // 0..60
  #pragma unroll
  for (int rr=0; rr<4; rr++){
    int row = cr + rr*16;
    u16x4 v = *(const u16x4*)(in + ibase + (long)(l0+row)*1024 + d0 + cc);
    *(u16x4*)&tile[row][cc] = v;
  }
  __syncthreads();
  #pragma unroll
  for (int rr=0; rr<4; rr++){
    int drow = cr + rr*16;
    u16x4 y;
    y[0] = tile[cc+0][drow];
    y[1] = tile[cc+1][drow];
    y[2] = tile[cc+2][drow];
    y[3] = tile[cc+3][drow];
    *(u16x4*)(outp + ibase + (long)(d0+drow)*1024 + l0 + cc) = y;
  }
}

// ---------------- pure-bf16 128x128 GEMM, C = A * B^T (m97 structure) ----------------
// A: M x K (K-contig), B: N x K (K-contig). 1D grid with XCD-chunk swizzle.
// MODE 0: C_f32 = acc*scale                    (QK -> scores)
// MODE 1: bf16-store acc -> cB                 (PV -> ctx)
// MODE 2: relu(acc+bias) -> bf16 cB            (FFN1 -> y1)
// MODE 3: acc+bias+res(bf16) -> C_f32          (FFN2 -> pre-LN)
template<int MODE>
__global__ __launch_bounds__(256) void gemm1(
    const u16* __restrict__ aB, const u16* __restrict__ bB,
    int K, int lda, int ldb, int ldc,
    long strideA, long strideB, long strideC,
    int gridN, int gridM,
    float scale, const float* __restrict__ bias,
    const u16* __restrict__ res,
    float* __restrict__ cF, u16* __restrict__ cB)
{
  __shared__ __align__(16) u16 sm[8192];   // A | B, each 128x32 bf16 (4096 u16)
  const int t = threadIdx.x;
  const int w = t >> 6;
  const int lane = t & 63;

  // XCD-chunk swizzle (bijective: gridDim.x % 8 == 0)
  const int p = blockIdx.x;
  const int chunk = gridDim.x >> 3;
  const int id = (p & 7) * chunk + (p >> 3);
  const int per = gridN * gridM;
  const long bz = id / per;
  const int rem = id % per;
  const int m0 = (rem / gridN) << 7, n0 = (rem % gridN) << 7;

  const u16* a = aB + bz * strideA;
  const u16* b = bB + bz * strideB;

  // staging: LDS unit u (16B): row = u>>2, slot = u&3, addr = row*32 + slot*8 (u16).
  // XOR swizzle: physical slot holds logical k-slot  slot ^ ((row>>1)&3)  -> conflict-free ds_read_b128.
  const int rA0 = t >> 2;
  const int rA1 = 64 + rA0;
  const int s0 = (t & 3) ^ ((rA0 >> 1) & 3);
  const int s1 = (t & 3) ^ ((rA1 >> 1) & 3);
  const u16* gA0 = a + (long)(m0 + rA0) * lda + s0 * 8;
  const u16* gA1 = a + (long)(m0 + rA1) * lda + s1 * 8;
  const u16* gB0 = b + (long)(n0 + rA0) * ldb + s0 * 8;
  const u16* gB1 = b + (long)(n0 + rA1) * ldb + s1 * 8;
  u16* ldsW = sm + (w << 9);   // wave-uniform base (w*512 u16 = 16 rows)

  f32x4 acc[4][4];
  #pragma unroll
  for (int i=0;i<4;i++)
    #pragma unroll
    for (int j=0;j<4;j++) acc[i][j] = (f32x4){0.f,0.f,0.f,0.f};

  const int fr = lane & 15, fs = lane >> 4;
  int offA[4], offB[4];
  #pragma unroll
  for (int i=0;i<4;i++){
    int ra = (w >> 1)*64 + i*16 + fr;
    offA[i] = ra*32 + (fs ^ ((ra>>1)&3))*8;
    int rb = (w & 1)*64 + i*16 + fr;
    offB[i] = rb*32 + (fs ^ ((rb>>1)&3))*8;
  }

  for (int k0 = 0; k0 < K; k0 += 32){
    async16(gA0 + k0, ldsW + 0);
    async16(gA1 + k0, ldsW + 2048);
    async16(gB0 + k0, ldsW + 4096);
    async16(gB1 + k0, ldsW + 6144);
    __syncthreads();
    short8 ah[4];
    #pragma unroll
    for (int i=0;i<4;i++) ah[i] = *(const short8*)(sm + offA[i]);
    #pragma unroll
    for (int j=0;j<4;j++){
      short8 bh = *(const short8*)(sm + 4096 + offB[j]);
      #pragma unroll
      for (int i=0;i<4;i++)
        acc[i][j] = __builtin_amdgcn_mfma_f32_16x16x32_bf16(ah[i], bh, acc[i][j], 0,0,0);
    }
    __syncthreads();
  }

  const long cBase = bz * strideC;
  const int colb = n0 + (w & 1)*64 + fr;
  const int rowb = m0 + (w >> 1)*64 + fs*4;
  #pragma unroll
  for (int j=0;j<4;j++){
    const int c = colb + j*16;
    float bv = 0.f;
    if constexpr (MODE == 2 || MODE == 3) bv = bias[c];
    #pragma unroll
    for (int i=0;i<4;i++){
      #pragma unroll
      for (int q=0;q<4;q++){
        const int r = rowb + i*16 + q;
        const long idx = cBase + (long)r*ldc + c;
        float v = acc[i][j][q];
        if constexpr (MODE == 0){
          cF[idx] = v * scale;
        } else if constexpr (MODE == 1){
          cB[idx] = f2bf(v);
        } else if constexpr (MODE == 2){
          cB[idx] = f2bf(fmaxf(v + bv, 0.f));
        } else {
          cF[idx] = v + bv + bf2f(res[idx]);
        }
      }
    }
  }
}

// ---------------- row softmax over 1024, writes probs fp32 (in place, in d_out) + bf16 ----------------
__global__ __launch_bounds__(256) void k_softmax(float* __restrict__ p, u16* __restrict__ pB){
  const long row = blockIdx.x;
  float* pr = p + row * 1024;
  const int t = threadIdx.x, w = t >> 6, lane = t & 63;
  __shared__ float rA[4], rB[4];
  f32x4 v = *(const f32x4*)(pr + t*4);
  float m = fmaxf(fmaxf(v[0],v[1]), fmaxf(v[2],v[3]));
  #pragma unroll
  for (int off=32; off; off>>=1) m = fmaxf(m, __shfl_xor(m, off));
  if (lane==0) rA[w] = m;
  __syncthreads();
  m = fmaxf(fmaxf(rA[0],rA[1]), fmaxf(rA[2],rA[3]));
  float e[4]; float s = 0.f;
  #pragma unroll
  for (int j=0;j<4;j++){ e[j] = expf(v[j]-m); s += e[j]; }
  #pragma unroll
  for (int off=32; off; off>>=1) s += __shfl_xor(s, off);
  if (lane==0) rB[w] = s;
  __syncthreads();
  s = rB[0]+rB[1]+rB[2]+rB[3];
  const float inv = 1.0f / s;
  f32x4 o; u16x4 hh;
  #pragma unroll
  for (int j=0;j<4;j++){
    float pv = e[j]*inv; o[j] = pv; hh[j] = f2bf(pv);
  }
  *(f32x4*)(pr + t*4) = o;
  *(u16x4*)(pB + row*1024 + t*4) = hh;
}

// ---------------- layernorm over 1024, writes h bf16 ----------------
__global__ __launch_bounds__(256) void k_ln(const float* __restrict__ r,
                                            const float* __restrict__ g, const float* __restrict__ b,
                                            u16* __restrict__ h){
  const long row = blockIdx.x;
  const float* rr = r + row * 1024;
  const int t = threadIdx.x, w = t >> 6, lane = t & 63;
  __shared__ float rA[4], rB[4];
  f32x4 v = *(const f32x4*)(rr + t*4);
  float s = v[0]+v[1]+v[2]+v[3];
  #pragma unroll
  for (int off=32; off; off>>=1) s += __shfl_xor(s, off);
  if (lane==0) rA[w] = s;
  __syncthreads();
  const float mu = (rA[0]+rA[1]+rA[2]+rA[3]) * (1.0f/1024.0f);
  float sq = 0.f;
  #pragma unroll
  for (int j=0;j<4;j++){ float d = v[j]-mu; sq += d*d; }
  #pragma unroll
  for (int off=32; off; off>>=1) sq += __shfl_xor(sq, off);
  if (lane==0) rB[w] = sq;
  __syncthreads();
  const float var = (rB[0]+rB[1]+rB[2]+rB[3]) * (1.0f/1024.0f);
  const float inv = rsqrtf(var + 1e-5f);
  u16x4 hh;
  #pragma unroll
  for (int j=0;j<4;j++){
    int d = t*4+j;
    hh[j] = f2bf((v[j]-mu)*inv*g[d] + b[d]);
  }
  *(u16x4*)(h + row*1024 + t*4) = hh;
}

// ---------------- final head ----------------
__global__ __launch_bounds__(256) void k_final1(const u16* __restrict__ h,
                                                const float* __restrict__ fw, const float* __restrict__ fb,
                                                float* __restrict__ z){
  const int row = blockIdx.x*4 + (threadIdx.x>>6);
  const int lane = threadIdx.x & 63;
  const long base = (long)row * 1024;
  const int d0 = lane * 16;
  float s = 0.f;
  #pragma unroll
  for (int j=0;j<16;j++){
    int d = d0 + j;
    s += bf2f(h[base+d]) * fw[d];
  }
  #pragma unroll
  for (int off=32; off; off>>=1) s += __shfl_xor(s, off);
  if (lane==0) z[row] = s + fb[0];
}

__global__ __launch_bounds__(256) void k_final2(const float* __restrict__ z,
                                                const float* __restrict__ fw, const float* __restrict__ fb,
                                                float* __restrict__ out){
  const int idx = blockIdx.x*4 + (threadIdx.x>>6);   // 0..383 = b*24+o
  const int lane = threadIdx.x & 63;
  const int b = idx / 24, o = idx % 24;
  float s = 0.f;
  #pragma unroll
  for (int j=0;j<16;j++){
    int li = lane + j*64;
    s += z[b*1024 + li] * fw[o*1024 + li];
  }
  #pragma unroll
  for (int off=32; off; off>>=1) s += __shfl_xor(s, off);
  if (lane==0) out[idx] = s + fb[o];
}

// ---------------- launch ----------------
extern "C" void kernel_launch(void* const* d_in, const int* in_sizes, int n_in,
                              void* d_out, int out_size, void* d_ws, size_t ws_size,
                              hipStream_t stream){
  const float* x   = (const float*)d_in[0];
  const float* pe  = (const float*)d_in[1];
  const float* w1  = (const float*)d_in[2];
  const float* b1  = (const float*)d_in[3];
  const float* w2  = (const float*)d_in[4];
  const float* b2  = (const float*)d_in[5];
  const float* lng = (const float*)d_in[6];
  const float* lnb = (const float*)d_in[7];
  const float* fcw = (const float*)d_in[8];
  const float* fcb = (const float*)d_in[9];
  const float* fw  = (const float*)d_in[10];
  const float* fb  = (const float*)d_in[11];
  float* out  = (float*)d_out;
  float* attn = out + 384;                 // (3,16,1024,1024) fp32

  char* ws = (char*)d_ws;
  const long BB = 32l*1024*1024;           // bf16 (B,L,D) buffer bytes
  u16* hB = (u16*)(ws + 0*BB);
  u16* tB = (u16*)(ws + 1*BB);             // h^T
  u16* cB = (u16*)(ws + 2*BB);             // ctx
  u16* pB = (u16*)(ws + 3*BB);             // probs (reused as y1)
  float* rf = (float*)(ws + 4*BB);         // pre-LN f32 (64MB)
  u16* w1B = (u16*)(ws + 6*BB);
  u16* w2B = w1B + 3l*1024*1024;
  float* z = (float*)(w2B + 3l*1024*1024); // (B,L) = 64KB

  const long M1 = 1024l*1024;

  k_split<<<3072, 256, 0, stream>>>(w1, w1B);
  k_split<<<3072, 256, 0, stream>>>(w2, w2B);
  k_addpe<<<16384, 256, 0, stream>>>(x, pe, hB);
  k_transpose<<<dim3(16,16,16), 256, 0, stream>>>(hB, tB);

  for (int l = 0; l < 3; l++){
    float* sc = attn + (long)l*16*M1;
    // scores = h h^T / 32  -> d_out
    gemm1<0><<<1024, 256, 0, stream>>>(hB, hB, 1024,1024,1024,1024,
        M1,M1,M1, 8,8, 0.03125f, nullptr, nullptr, sc, nullptr);
    // softmax in place + bf16 probs
    k_softmax<<<16384, 256, 0, stream>>>(sc, pB);
    // ctx = P h   (B = h^T, K-contig)
    gemm1<1><<<1024, 256, 0, stream>>>(pB, tB, 1024,1024,1024,1024,
        M1,M1,M1, 8,8, 1.f, nullptr, nullptr, nullptr, cB);
    // y1 = relu(ctx w1^T + b1)
    gemm1<2><<<1024, 256, 0, stream>>>(cB, w1B+l*M1, 1024,1024,1024,1024,
        0,0,0, 8,128, 1.f, b1+l*1024, nullptr, nullptr, pB);
    // rf = y1 w2^T + b2 + ctx
    gemm1<3><<<1024, 256, 0, stream>>>(pB, w2B+l*M1, 1024,1024,1024,1024,
        0,0,0, 8,128, 1.f, b2+l*1024, cB, rf, nullptr);
    // h = LN(rf)*g + b
    k_ln<<<16384, 256, 0, stream>>>(rf, lng+l*1024, lnb+l*1024, hB);
    if (l < 2) k_transpose<<<dim3(16,16,16), 256, 0, stream>>>(hB, tB);
  }

  k_final1<<<4096, 256, 0, stream>>>(hB, fcw, fcb, z);
  k_final2<<<96, 256, 0, stream>>>(z, fw, fb, out);
}

// Round 3
// 744.994 us; speedup vs baseline: 2.7126x; 1.1834x over previous
//
#include <hip/hip_runtime.h>

typedef unsigned short u16;
typedef __attribute__((ext_vector_type(8))) short short8;
typedef __attribute__((ext_vector_type(4))) float f32x4;
typedef __attribute__((ext_vector_type(4))) unsigned short u16x4;

__device__ __forceinline__ float bf2f(u16 u){
  union { unsigned int i; float f; } x; x.i = ((unsigned int)u) << 16; return x.f;
}
__device__ __forceinline__ u16 f2bf(float f){
  union { float f; unsigned int i; } x; x.f = f;
  return (u16)((x.i + 0x7fffu + ((x.i >> 16) & 1u)) >> 16);
}
__device__ __forceinline__ void async16(const void* g, void* s){
  __builtin_amdgcn_global_load_lds((const __attribute__((address_space(1))) void*)g,
                                   (__attribute__((address_space(3))) void*)s, 16, 0, 0);
}

// ---------------- elementwise bf16-cast kernels ----------------
__global__ __launch_bounds__(256) void k_split(const float* __restrict__ s, u16* __restrict__ d){
  long i = ((long)blockIdx.x * 256 + threadIdx.x) * 4;
  f32x4 v = *(const f32x4*)(s + i);
  u16x4 hh;
  #pragma unroll
  for (int j=0;j<4;j++) hh[j] = f2bf(v[j]);
  *(u16x4*)(d+i) = hh;
}

__global__ __launch_bounds__(256) void k_addpe(const float* __restrict__ x, const float* __restrict__ pe,
                                               u16* __restrict__ d){
  long i = ((long)blockIdx.x * 256 + threadIdx.x) * 4;
  f32x4 xv = *(const f32x4*)(x + i);
  f32x4 pv = *(const f32x4*)(pe + (i & 1048575));
  u16x4 hh;
  #pragma unroll
  for (int j=0;j<4;j++) hh[j] = f2bf(xv[j]+pv[j]);
  *(u16x4*)(d+i) = hh;
}

// ---------------- 64x64 tiled transpose, (B,L,D)->(B,D,L) ----------------
__global__ __launch_bounds__(256) void k_transpose(const u16* __restrict__ in, u16* __restrict__ outp){
  __shared__ u16 tile[64][68];
  const long b = blockIdx.z;
  const int d0 = blockIdx.x * 64, l0 = blockIdx.y * 64;
  const long ibase = b * 1048576l;
  const int t = threadIdx.x;
  const int cr = t >> 4;
  const int cc = (t & 15) * 4;
  #pragma unroll
  for (int rr=0; rr<4; rr++){
    int row = cr + rr*16;
    u16x4 v = *(const u16x4*)(in + ibase + (long)(l0+row)*1024 + d0 + cc);
    *(u16x4*)&tile[row][cc] = v;
  }
  __syncthreads();
  #pragma unroll
  for (int rr=0; rr<4; rr++){
    int drow = cr + rr*16;
    u16x4 y;
    y[0] = tile[cc+0][drow];
    y[1] = tile[cc+1][drow];
    y[2] = tile[cc+2][drow];
    y[3] = tile[cc+3][drow];
    *(u16x4*)(outp + ibase + (long)(d0+drow)*1024 + l0 + cc) = y;
  }
}

// ---------------- 256x256 8-wave deep-pipelined bf16 GEMM, C = A * B^T ----------------
// BK=32, 4-buffer LDS ring (128 KB), counted vmcnt(8) — loads span 3 K-tiles.
// K hardcoded 1024 (32 K-tiles). Grid must be 256 (per*batches/ffn-tiles), 512 threads.
// MODE 0: C_f32 = acc*scale ; MODE 1: bf16 acc ; MODE 2: relu(acc+bias)->bf16 ;
// MODE 3: acc+bias+res(bf16) -> f32
template<int MODE>
__global__ __launch_bounds__(512, 2) void gemm8(
    const u16* __restrict__ aB, const u16* __restrict__ bB,
    int per, long sA, long sB, long sC,
    int lda, int ldb, int ldc,
    float scale, const float* __restrict__ bias,
    const u16* __restrict__ res,
    float* __restrict__ cF, u16* __restrict__ cB)
{
  __shared__ __align__(16) u16 sm[65536];   // 4 bufs x (A 256x32 | B 256x32) = 4 x 16384 u16
  const int t = threadIdx.x;
  const int w = t >> 6, lane = t & 63;
  const int wm = w >> 2, wn = w & 3;
  const int fr = lane & 15, fs = lane >> 4;

  // XCD chunk swizzle (bijective: 256 % 8 == 0)
  const int p = blockIdx.x;
  const int chunk = gridDim.x >> 3;
  const int id = (p & 7) * chunk + (p >> 3);
  const long bz = id / per;
  const int rem = id % per;
  const int m0 = (rem >> 2) << 8, n0 = (rem & 3) << 8;

  const u16* a = aB + bz * sA;
  const u16* b = bB + bz * sB;

  // ---- staging addresses (pre-swizzled global source; LDS linear) ----
  // unit u within half-tile chunk: row = u>>2, phys slot = u&3 holds logical slot
  // (u&3) ^ ((row>>1)&3)  -> conflict-free ds_read_b128 on the read side.
  const int urow = t >> 2;
  const int col8 = ((t & 3) ^ ((t >> 3) & 3)) * 8;
  const u16* gA0 = a + (long)(m0 + urow) * lda + col8;
  const u16* gA1 = a + (long)(m0 + 128 + urow) * lda + col8;
  const u16* gB0 = b + (long)(n0 + urow) * ldb + col8;
  const u16* gB1 = b + (long)(n0 + 128 + urow) * ldb + col8;
  u16* dA0 = sm + (w << 9);              // wave-uniform dests
  u16* dA1 = sm + 4096 + (w << 9);
  u16* dB0 = sm + 8192 + (w << 9);
  u16* dB1 = sm + 12288 + (w << 9);

  // ---- fragment read offsets (u16 units, swizzled) ----
  int offA[8], offB[4];
  #pragma unroll
  for (int i=0;i<8;i++){
    int row = wm*128 + i*16 + fr;
    int sl = fs ^ ((row >> 1) & 3);
    offA[i] = row*32 + sl*8;
  }
  #pragma unroll
  for (int j=0;j<4;j++){
    int row = wn*64 + j*16 + fr;
    int sl = fs ^ ((row >> 1) & 3);
    offB[j] = 8192 + row*32 + sl*8;
  }

  f32x4 acc[8][4];
  #pragma unroll
  for (int i=0;i<8;i++)
    #pragma unroll
    for (int j=0;j<4;j++) acc[i][j] = (f32x4){0.f,0.f,0.f,0.f};

  // ---- prologue: stage K-tiles 0,1,2 into bufs 0,1,2 ----
  #pragma unroll
  for (int pb=0; pb<3; ++pb){
    const int kb = pb*32, sb = pb*16384;
    async16(gA0+kb, dA0+sb); async16(gA1+kb, dA1+sb);
    async16(gB0+kb, dB0+sb); async16(gB1+kb, dB1+sb);
  }
  gA0 += 96; gA1 += 96; gB0 += 96; gB1 += 96;
  asm volatile("s_waitcnt vmcnt(8)" ::: "memory");   // buf0 resident (8 = tiles 1,2 in flight)
  __builtin_amdgcn_s_barrier();
  __builtin_amdgcn_sched_barrier(0);

#define KT_COMPUTE(SMB)                                                        \
    short8 aF[8];                                                              \
    _Pragma("unroll")                                                          \
    for (int i=0;i<8;i++) aF[i] = *(const short8*)((SMB) + offA[i]);           \
    short8 bF0 = *(const short8*)((SMB) + offB[0]);                            \
    short8 bF1 = *(const short8*)((SMB) + offB[1]);

#define KT_MFMA01                                                              \
    __builtin_amdgcn_s_barrier();                                              \
    __builtin_amdgcn_sched_barrier(0);                                         \
    __builtin_amdgcn_s_setprio(1);                                             \
    _Pragma("unroll")                                                          \
    for (int i=0;i<8;i++){                                                     \
      acc[i][0] = __builtin_amdgcn_mfma_f32_16x16x32_bf16(aF[i], bF0, acc[i][0], 0,0,0); \
      acc[i][1] = __builtin_amdgcn_mfma_f32_16x16x32_bf16(aF[i], bF1, acc[i][1], 0,0,0); \
    }                                                                          \
    __builtin_amdgcn_s_setprio(0);                                             \
    __builtin_amdgcn_s_barrier();

#define KT_MFMA23(SMB)                                                         \
    short8 bF2 = *(const short8*)((SMB) + offB[2]);                            \
    short8 bF3 = *(const short8*)((SMB) + offB[3]);                            \
    __builtin_amdgcn_s_setprio(1);                                             \
    _Pragma("unroll")                                                          \
    for (int i=0;i<8;i++){                                                     \
      acc[i][2] = __builtin_amdgcn_mfma_f32_16x16x32_bf16(aF[i], bF2, acc[i][2], 0,0,0); \
      acc[i][3] = __builtin_amdgcn_mfma_f32_16x16x32_bf16(aF[i], bF3, acc[i][3], 0,0,0); \
    }                                                                          \
    __builtin_amdgcn_s_setprio(0);

  // ---- main loop: K-tiles 0..28 stage kt+3 and wait counted vmcnt(8) ----
  for (int kt = 0; kt < 29; ++kt){
    const u16* smb = sm + (kt & 3)*16384;
    const int sb = ((kt + 3) & 3)*16384;
    KT_COMPUTE(smb)
    async16(gA0, dA0+sb); async16(gA1, dA1+sb);
    async16(gB0, dB0+sb); async16(gB1, dB1+sb);
    gA0 += 32; gA1 += 32; gB0 += 32; gB1 += 32;
    KT_MFMA01
    KT_MFMA23(smb)
    asm volatile("s_waitcnt vmcnt(8)" ::: "memory");  // kt+1 resident; kt+2,kt+3 in flight
    __builtin_amdgcn_s_barrier();
    __builtin_amdgcn_sched_barrier(0);
  }
  // ---- tail: kt=29,30,31 (no staging; drain 4, 0, none) ----
  {
    const u16* smb = sm + (29 & 3)*16384;
    KT_COMPUTE(smb)
    KT_MFMA01
    KT_MFMA23(smb)
    asm volatile("s_waitcnt vmcnt(4)" ::: "memory");
    __builtin_amdgcn_s_barrier();
    __builtin_amdgcn_sched_barrier(0);
  }
  {
    const u16* smb = sm + (30 & 3)*16384;
    KT_COMPUTE(smb)
    KT_MFMA01
    KT_MFMA23(smb)
    asm volatile("s_waitcnt vmcnt(0)" ::: "memory");
    __builtin_amdgcn_s_barrier();
    __builtin_amdgcn_sched_barrier(0);
  }
  {
    const u16* smb = sm + (31 & 3)*16384;
    KT_COMPUTE(smb)
    KT_MFMA01
    KT_MFMA23(smb)
  }
#undef KT_COMPUTE
#undef KT_MFMA01
#undef KT_MFMA23

  // ---- epilogue ----
  const long cBase = bz * sC;
  const int rb = m0 + wm*128 + fs*4;
  const int cb = n0 + wn*64 + fr;
  #pragma unroll
  for (int j=0;j<4;j++){
    const int c = cb + j*16;
    float bv = 0.f;
    if constexpr (MODE == 2 || MODE == 3) bv = bias[c];
    #pragma unroll
    for (int i=0;i<8;i++){
      #pragma unroll
      for (int q=0;q<4;q++){
        const int r = rb + i*16 + q;
        const long idx = cBase + (long)r*ldc + c;
        float v = acc[i][j][q];
        if constexpr (MODE == 0){
          cF[idx] = v * scale;
        } else if constexpr (MODE == 1){
          cB[idx] = f2bf(v);
        } else if constexpr (MODE == 2){
          cB[idx] = f2bf(fmaxf(v + bv, 0.f));
        } else {
          cF[idx] = v + bv + bf2f(res[idx]);
        }
      }
    }
  }
}

// ---------------- row softmax over 1024, probs fp32 (in place, in d_out) + bf16 ----------------
__global__ __launch_bounds__(256) void k_softmax(float* __restrict__ p, u16* __restrict__ pB){
  const long row = blockIdx.x;
  float* pr = p + row * 1024;
  const int t = threadIdx.x, w = t >> 6, lane = t & 63;
  __shared__ float rA[4], rB[4];
  f32x4 v = *(const f32x4*)(pr + t*4);
  float m = fmaxf(fmaxf(v[0],v[1]), fmaxf(v[2],v[3]));
  #pragma unroll
  for (int off=32; off; off>>=1) m = fmaxf(m, __shfl_xor(m, off));
  if (lane==0) rA[w] = m;
  __syncthreads();
  m = fmaxf(fmaxf(rA[0],rA[1]), fmaxf(rA[2],rA[3]));
  float e[4]; float s = 0.f;
  #pragma unroll
  for (int j=0;j<4;j++){ e[j] = expf(v[j]-m); s += e[j]; }
  #pragma unroll
  for (int off=32; off; off>>=1) s += __shfl_xor(s, off);
  if (lane==0) rB[w] = s;
  __syncthreads();
  s = rB[0]+rB[1]+rB[2]+rB[3];
  const float inv = 1.0f / s;
  f32x4 o; u16x4 hh;
  #pragma unroll
  for (int j=0;j<4;j++){
    float pv = e[j]*inv; o[j] = pv; hh[j] = f2bf(pv);
  }
  *(f32x4*)(pr + t*4) = o;
  *(u16x4*)(pB + row*1024 + t*4) = hh;
}

// ---------------- layernorm over 1024, writes h bf16 ----------------
__global__ __launch_bounds__(256) void k_ln(const float* __restrict__ r,
                                            const float* __restrict__ g, const float* __restrict__ b,
                                            u16* __restrict__ h){
  const long row = blockIdx.x;
  const float* rr = r + row * 1024;
  const int t = threadIdx.x, w = t >> 6, lane = t & 63;
  __shared__ float rA[4], rB[4];
  f32x4 v = *(const f32x4*)(rr + t*4);
  float s = v[0]+v[1]+v[2]+v[3];
  #pragma unroll
  for (int off=32; off; off>>=1) s += __shfl_xor(s, off);
  if (lane==0) rA[w] = s;
  __syncthreads();
  const float mu = (rA[0]+rA[1]+rA[2]+rA[3]) * (1.0f/1024.0f);
  float sq = 0.f;
  #pragma unroll
  for (int j=0;j<4;j++){ float d = v[j]-mu; sq += d*d; }
  #pragma unroll
  for (int off=32; off; off>>=1) sq += __shfl_xor(sq, off);
  if (lane==0) rB[w] = sq;
  __syncthreads();
  const float var = (rB[0]+rB[1]+rB[2]+rB[3]) * (1.0f/1024.0f);
  const float inv = rsqrtf(var + 1e-5f);
  u16x4 hh;
  #pragma unroll
  for (int j=0;j<4;j++){
    int d = t*4+j;
    hh[j] = f2bf((v[j]-mu)*inv*g[d] + b[d]);
  }
  *(u16x4*)(h + row*1024 + t*4) = hh;
}

// ---------------- final head ----------------
__global__ __launch_bounds__(256) void k_final1(const u16* __restrict__ h,
                                                const float* __restrict__ fw, const float* __restrict__ fb,
                                                float* __restrict__ z){
  const int row = blockIdx.x*4 + (threadIdx.x>>6);
  const int lane = threadIdx.x & 63;
  const long base = (long)row * 1024;
  const int d0 = lane * 16;
  float s = 0.f;
  #pragma unroll
  for (int j=0;j<16;j++){
    int d = d0 + j;
    s += bf2f(h[base+d]) * fw[d];
  }
  #pragma unroll
  for (int off=32; off; off>>=1) s += __shfl_xor(s, off);
  if (lane==0) z[row] = s + fb[0];
}

__global__ __launch_bounds__(256) void k_final2(const float* __restrict__ z,
                                                const float* __restrict__ fw, const float* __restrict__ fb,
                                                float* __restrict__ out){
  const int idx = blockIdx.x*4 + (threadIdx.x>>6);
  const int lane = threadIdx.x & 63;
  const int b = idx / 24, o = idx % 24;
  float s = 0.f;
  #pragma unroll
  for (int j=0;j<16;j++){
    int li = lane + j*64;
    s += z[b*1024 + li] * fw[o*1024 + li];
  }
  #pragma unroll
  for (int off=32; off; off>>=1) s += __shfl_xor(s, off);
  if (lane==0) out[idx] = s + fb[o];
}

// ---------------- launch ----------------
extern "C" void kernel_launch(void* const* d_in, const int* in_sizes, int n_in,
                              void* d_out, int out_size, void* d_ws, size_t ws_size,
                              hipStream_t stream){
  const float* x   = (const float*)d_in[0];
  const float* pe  = (const float*)d_in[1];
  const float* w1  = (const float*)d_in[2];
  const float* b1  = (const float*)d_in[3];
  const float* w2  = (const float*)d_in[4];
  const float* b2  = (const float*)d_in[5];
  const float* lng = (const float*)d_in[6];
  const float* lnb = (const float*)d_in[7];
  const float* fcw = (const float*)d_in[8];
  const float* fcb = (const float*)d_in[9];
  const float* fw  = (const float*)d_in[10];
  const float* fb  = (const float*)d_in[11];
  float* out  = (float*)d_out;
  float* attn = out + 384;                 // (3,16,1024,1024) fp32

  char* ws = (char*)d_ws;
  const long BB = 32l*1024*1024;           // bf16 (B,L,D) buffer bytes
  u16* hB = (u16*)(ws + 0*BB);
  u16* tB = (u16*)(ws + 1*BB);             // h^T
  u16* cB = (u16*)(ws + 2*BB);             // ctx
  u16* pB = (u16*)(ws + 3*BB);             // probs (reused as y1)
  float* rf = (float*)(ws + 4*BB);         // pre-LN f32 (64MB)
  u16* w1B = (u16*)(ws + 6*BB);
  u16* w2B = w1B + 3l*1024*1024;
  float* z = (float*)(w2B + 3l*1024*1024); // (B,L) = 64KB

  const long M1 = 1024l*1024;

  k_split<<<3072, 256, 0, stream>>>(w1, w1B);
  k_split<<<3072, 256, 0, stream>>>(w2, w2B);
  k_addpe<<<16384, 256, 0, stream>>>(x, pe, hB);
  k_transpose<<<dim3(16,16,16), 256, 0, stream>>>(hB, tB);

  for (int l = 0; l < 3; l++){
    float* sc = attn + (long)l*16*M1;
    // scores = h h^T / 32  -> d_out   (16 batches x 4x4 tiles = 256 wg)
    gemm8<0><<<256, 512, 0, stream>>>(hB, hB, 16, M1,M1,M1, 1024,1024,1024,
        0.03125f, nullptr, nullptr, sc, nullptr);
    // softmax in place + bf16 probs
    k_softmax<<<16384, 256, 0, stream>>>(sc, pB);
    // ctx = P h   (B = h^T, K-contig)
    gemm8<1><<<256, 512, 0, stream>>>(pB, tB, 16, M1,M1,M1, 1024,1024,1024,
        1.f, nullptr, nullptr, nullptr, cB);
    // y1 = relu(ctx w1^T + b1)   (64x4 tiles = 256 wg)
    gemm8<2><<<256, 512, 0, stream>>>(cB, w1B+l*M1, 256, 0,0,0, 1024,1024,1024,
        1.f, b1+l*1024, nullptr, nullptr, pB);
    // rf = y1 w2^T + b2 + ctx
    gemm8<3><<<256, 512, 0, stream>>>(pB, w2B+l*M1, 256, 0,0,0, 1024,1024,1024,
        1.f, b2+l*1024, cB, rf, nullptr);
    // h = LN(rf)*g + b
    k_ln<<<16384, 256, 0, stream>>>(rf, lng+l*1024, lnb+l*1024, hB);
    if (l < 2) k_transpose<<<dim3(16,16,16), 256, 0, stream>>>(hB, tB);
  }

  k_final1<<<4096, 256, 0, stream>>>(hB, fcw, fcb, z);
  k_final2<<<96, 256, 0, stream>>>(z, fw, fb, out);
}

// Round 4
// 734.960 us; speedup vs baseline: 2.7496x; 1.0137x over previous
//
#include <hip/hip_runtime.h>

typedef unsigned short u16;
typedef __attribute__((ext_vector_type(8))) short short8;
typedef __attribute__((ext_vector_type(4))) float f32x4;
typedef __attribute__((ext_vector_type(4))) unsigned short u16x4;

__device__ __forceinline__ float bf2f(u16 u){
  union { unsigned int i; float f; } x; x.i = ((unsigned int)u) << 16; return x.f;
}
__device__ __forceinline__ u16 f2bf(float f){
  union { float f; unsigned int i; } x; x.f = f;
  return (u16)((x.i + 0x7fffu + ((x.i >> 16) & 1u)) >> 16);
}
__device__ __forceinline__ void async16(const void* g, void* s){
  __builtin_amdgcn_global_load_lds((const __attribute__((address_space(1))) void*)g,
                                   (__attribute__((address_space(3))) void*)s, 16, 0, 0);
}

// ---------------- elementwise bf16-cast kernels ----------------
__global__ __launch_bounds__(256) void k_split2(const float* __restrict__ s1, u16* __restrict__ d1,
                                                const float* __restrict__ s2, u16* __restrict__ d2){
  long i = ((long)blockIdx.x * 256 + threadIdx.x) * 4;
  f32x4 v1 = *(const f32x4*)(s1 + i);
  f32x4 v2 = *(const f32x4*)(s2 + i);
  u16x4 h1, h2;
  #pragma unroll
  for (int j=0;j<4;j++){ h1[j] = f2bf(v1[j]); h2[j] = f2bf(v2[j]); }
  *(u16x4*)(d1+i) = h1;
  *(u16x4*)(d2+i) = h2;
}

__global__ __launch_bounds__(256) void k_addpe(const float* __restrict__ x, const float* __restrict__ pe,
                                               u16* __restrict__ d){
  long i = ((long)blockIdx.x * 256 + threadIdx.x) * 4;
  f32x4 xv = *(const f32x4*)(x + i);
  f32x4 pv = *(const f32x4*)(pe + (i & 1048575));
  u16x4 hh;
  #pragma unroll
  for (int j=0;j<4;j++) hh[j] = f2bf(xv[j]+pv[j]);
  *(u16x4*)(d+i) = hh;
}

// ---------------- 64x64 tiled transpose, (B,L,D)->(B,D,L) ----------------
__global__ __launch_bounds__(256) void k_transpose(const u16* __restrict__ in, u16* __restrict__ outp){
  __shared__ u16 tile[64][68];
  const long b = blockIdx.z;
  const int d0 = blockIdx.x * 64, l0 = blockIdx.y * 64;
  const long ibase = b * 1048576l;
  const int t = threadIdx.x;
  const int cr = t >> 4;
  const int cc = (t & 15) * 4;
  #pragma unroll
  for (int rr=0; rr<4; rr++){
    int row = cr + rr*16;
    u16x4 v = *(const u16x4*)(in + ibase + (long)(l0+row)*1024 + d0 + cc);
    *(u16x4*)&tile[row][cc] = v;
  }
  __syncthreads();
  #pragma unroll
  for (int rr=0; rr<4; rr++){
    int drow = cr + rr*16;
    u16x4 y;
    y[0] = tile[cc+0][drow];
    y[1] = tile[cc+1][drow];
    y[2] = tile[cc+2][drow];
    y[3] = tile[cc+3][drow];
    *(u16x4*)(outp + ibase + (long)(d0+drow)*1024 + l0 + cc) = y;
  }
}

// ---------------- 256x256 8-wave deep-pipelined bf16 GEMM, C = A * B^T ----------------
// BK=32, 4-buffer LDS ring (128 KB), counted vmcnt(8) — loads span 3 K-tiles.
// 2 barriers per K-tile: [stage-issue | ds_read x12 | barrier | MFMA x32 | vmcnt(8) | barrier]
// K hardcoded 1024 (32 K-tiles). Grid 256, 512 threads.
// MODE 0: C_f32 = acc*scale ; MODE 1: bf16 acc ; MODE 2: relu(acc+bias)->bf16 ;
// MODE 3: acc+bias+res(bf16) -> f32
template<int MODE>
__global__ __launch_bounds__(512, 2) void gemm8(
    const u16* __restrict__ aB, const u16* __restrict__ bB,
    int per, long sA, long sB, long sC,
    int lda, int ldb, int ldc,
    float scale, const float* __restrict__ bias,
    const u16* __restrict__ res,
    float* __restrict__ cF, u16* __restrict__ cB)
{
  __shared__ __align__(16) u16 sm[65536];   // 4 bufs x (A 256x32 | B 256x32) = 4 x 16384 u16
  const int t = threadIdx.x;
  const int w = t >> 6, lane = t & 63;
  const int wm = w >> 2, wn = w & 3;
  const int fr = lane & 15, fs = lane >> 4;

  // XCD chunk swizzle (bijective: 256 % 8 == 0)
  const int p = blockIdx.x;
  const int chunk = gridDim.x >> 3;
  const int id = (p & 7) * chunk + (p >> 3);
  const long bz = id / per;
  const int rem = id % per;
  const int m0 = (rem >> 2) << 8, n0 = (rem & 3) << 8;

  const u16* a = aB + bz * sA;
  const u16* b = bB + bz * sB;

  // ---- staging addresses (pre-swizzled global source; LDS linear) ----
  const int urow = t >> 2;
  const int col8 = ((t & 3) ^ ((t >> 3) & 3)) * 8;
  const u16* gA0 = a + (long)(m0 + urow) * lda + col8;
  const u16* gA1 = a + (long)(m0 + 128 + urow) * lda + col8;
  const u16* gB0 = b + (long)(n0 + urow) * ldb + col8;
  const u16* gB1 = b + (long)(n0 + 128 + urow) * ldb + col8;
  u16* dA0 = sm + (w << 9);              // wave-uniform dests
  u16* dA1 = sm + 4096 + (w << 9);
  u16* dB0 = sm + 8192 + (w << 9);
  u16* dB1 = sm + 12288 + (w << 9);

  // ---- fragment read offsets (u16 units, swizzled) ----
  int offA[8], offB[4];
  #pragma unroll
  for (int i=0;i<8;i++){
    int row = wm*128 + i*16 + fr;
    int sl = fs ^ ((row >> 1) & 3);
    offA[i] = row*32 + sl*8;
  }
  #pragma unroll
  for (int j=0;j<4;j++){
    int row = wn*64 + j*16 + fr;
    int sl = fs ^ ((row >> 1) & 3);
    offB[j] = 8192 + row*32 + sl*8;
  }

  f32x4 acc[8][4];
  #pragma unroll
  for (int i=0;i<8;i++)
    #pragma unroll
    for (int j=0;j<4;j++) acc[i][j] = (f32x4){0.f,0.f,0.f,0.f};

  // ---- prologue: stage K-tiles 0,1,2 into bufs 0,1,2 ----
  #pragma unroll
  for (int pb=0; pb<3; ++pb){
    const int kb = pb*32, sb = pb*16384;
    async16(gA0+kb, dA0+sb); async16(gA1+kb, dA1+sb);
    async16(gB0+kb, dB0+sb); async16(gB1+kb, dB1+sb);
  }
  gA0 += 96; gA1 += 96; gB0 += 96; gB1 += 96;
  asm volatile("s_waitcnt vmcnt(8)" ::: "memory");   // own tile-0 loads retired
  __builtin_amdgcn_s_barrier();                      // -> tile 0 resident for all
  __builtin_amdgcn_sched_barrier(0);

#define KT_BODY(SMB)                                                           \
    short8 aF[8], bF[4];                                                       \
    _Pragma("unroll")                                                          \
    for (int i=0;i<8;i++) aF[i] = *(const short8*)((SMB) + offA[i]);           \
    _Pragma("unroll")                                                          \
    for (int j=0;j<4;j++) bF[j] = *(const short8*)((SMB) + offB[j]);           \
    __builtin_amdgcn_s_barrier();                                              \
    __builtin_amdgcn_sched_barrier(0);                                         \
    __builtin_amdgcn_s_setprio(1);                                             \
    _Pragma("unroll")                                                          \
    for (int i=0;i<8;i++){                                                     \
      acc[i][0] = __builtin_amdgcn_mfma_f32_16x16x32_bf16(aF[i], bF[0], acc[i][0], 0,0,0); \
      acc[i][1] = __builtin_amdgcn_mfma_f32_16x16x32_bf16(aF[i], bF[1], acc[i][1], 0,0,0); \
    }                                                                          \
    _Pragma("unroll")                                                          \
    for (int i=0;i<8;i++){                                                     \
      acc[i][2] = __builtin_amdgcn_mfma_f32_16x16x32_bf16(aF[i], bF[2], acc[i][2], 0,0,0); \
      acc[i][3] = __builtin_amdgcn_mfma_f32_16x16x32_bf16(aF[i], bF[3], acc[i][3], 0,0,0); \
    }                                                                          \
    __builtin_amdgcn_s_setprio(0);

  // ---- main loop: K-tiles 0..28 stage kt+3, counted vmcnt(8) ----
  for (int kt = 0; kt < 29; ++kt){
    const u16* smb = sm + (kt & 3)*16384;
    const int sb = ((kt + 3) & 3)*16384;
    async16(gA0, dA0+sb); async16(gA1, dA1+sb);
    async16(gB0, dB0+sb); async16(gB1, dB1+sb);
    gA0 += 32; gA1 += 32; gB0 += 32; gB1 += 32;
    KT_BODY(smb)
    asm volatile("s_waitcnt vmcnt(8)" ::: "memory");  // own kt+1 loads retired
    __builtin_amdgcn_s_barrier();                     // -> kt+1 resident for all
    __builtin_amdgcn_sched_barrier(0);
  }
  // ---- tail: kt=29,30,31 (no staging; drain 4, 0, none) ----
  {
    const u16* smb = sm + (29 & 3)*16384;
    KT_BODY(smb)
    asm volatile("s_waitcnt vmcnt(4)" ::: "memory");
    __builtin_amdgcn_s_barrier();
    __builtin_amdgcn_sched_barrier(0);
  }
  {
    const u16* smb = sm + (30 & 3)*16384;
    KT_BODY(smb)
    asm volatile("s_waitcnt vmcnt(0)" ::: "memory");
    __builtin_amdgcn_s_barrier();
    __builtin_amdgcn_sched_barrier(0);
  }
  {
    const u16* smb = sm + (31 & 3)*16384;
    KT_BODY(smb)
  }
#undef KT_BODY

  // ---- epilogue ----
  const long cBase = bz * sC;
  const int rb = m0 + wm*128 + fs*4;
  const int cb = n0 + wn*64 + fr;
  #pragma unroll
  for (int j=0;j<4;j++){
    const int c = cb + j*16;
    float bv = 0.f;
    if constexpr (MODE == 2 || MODE == 3) bv = bias[c];
    #pragma unroll
    for (int i=0;i<8;i++){
      #pragma unroll
      for (int q=0;q<4;q++){
        const int r = rb + i*16 + q;
        const long idx = cBase + (long)r*ldc + c;
        float v = acc[i][j][q];
        if constexpr (MODE == 0){
          cF[idx] = v * scale;
        } else if constexpr (MODE == 1){
          cB[idx] = f2bf(v);
        } else if constexpr (MODE == 2){
          cB[idx] = f2bf(fmaxf(v + bv, 0.f));
        } else {
          cF[idx] = v + bv + bf2f(res[idx]);
        }
      }
    }
  }
}

// ---------------- row softmax over 1024, probs fp32 (in place, in d_out) + bf16 ----------------
__global__ __launch_bounds__(256) void k_softmax(float* __restrict__ p, u16* __restrict__ pB){
  const long row = blockIdx.x;
  float* pr = p + row * 1024;
  const int t = threadIdx.x, w = t >> 6, lane = t & 63;
  __shared__ float rA[4], rB[4];
  f32x4 v = *(const f32x4*)(pr + t*4);
  float m = fmaxf(fmaxf(v[0],v[1]), fmaxf(v[2],v[3]));
  #pragma unroll
  for (int off=32; off; off>>=1) m = fmaxf(m, __shfl_xor(m, off));
  if (lane==0) rA[w] = m;
  __syncthreads();
  m = fmaxf(fmaxf(rA[0],rA[1]), fmaxf(rA[2],rA[3]));
  float e[4]; float s = 0.f;
  #pragma unroll
  for (int j=0;j<4;j++){ e[j] = expf(v[j]-m); s += e[j]; }
  #pragma unroll
  for (int off=32; off; off>>=1) s += __shfl_xor(s, off);
  if (lane==0) rB[w] = s;
  __syncthreads();
  s = rB[0]+rB[1]+rB[2]+rB[3];
  const float inv = 1.0f / s;
  f32x4 o; u16x4 hh;
  #pragma unroll
  for (int j=0;j<4;j++){
    float pv = e[j]*inv; o[j] = pv; hh[j] = f2bf(pv);
  }
  *(f32x4*)(pr + t*4) = o;
  *(u16x4*)(pB + row*1024 + t*4) = hh;
}

// ---------------- layernorm over 1024, writes h bf16 ----------------
__global__ __launch_bounds__(256) void k_ln(const float* __restrict__ r,
                                            const float* __restrict__ g, const float* __restrict__ b,
                                            u16* __restrict__ h){
  const long row = blockIdx.x;
  const float* rr = r + row * 1024;
  const int t = threadIdx.x, w = t >> 6, lane = t & 63;
  __shared__ float rA[4], rB[4];
  f32x4 v = *(const f32x4*)(rr + t*4);
  float s = v[0]+v[1]+v[2]+v[3];
  #pragma unroll
  for (int off=32; off; off>>=1) s += __shfl_xor(s, off);
  if (lane==0) rA[w] = s;
  __syncthreads();
  const float mu = (rA[0]+rA[1]+rA[2]+rA[3]) * (1.0f/1024.0f);
  float sq = 0.f;
  #pragma unroll
  for (int j=0;j<4;j++){ float d = v[j]-mu; sq += d*d; }
  #pragma unroll
  for (int off=32; off; off>>=1) sq += __shfl_xor(sq, off);
  if (lane==0) rB[w] = sq;
  __syncthreads();
  const float var = (rB[0]+rB[1]+rB[2]+rB[3]) * (1.0f/1024.0f);
  const float inv = rsqrtf(var + 1e-5f);
  u16x4 hh;
  #pragma unroll
  for (int j=0;j<4;j++){
    int d = t*4+j;
    hh[j] = f2bf((v[j]-mu)*inv*g[d] + b[d]);
  }
  *(u16x4*)(h + row*1024 + t*4) = hh;
}

// ---------------- final head ----------------
__global__ __launch_bounds__(256) void k_final1(const u16* __restrict__ h,
                                                const float* __restrict__ fw, const float* __restrict__ fb,
                                                float* __restrict__ z){
  const int row = blockIdx.x*4 + (threadIdx.x>>6);
  const int lane = threadIdx.x & 63;
  const long base = (long)row * 1024;
  const int d0 = lane * 16;
  float s = 0.f;
  #pragma unroll
  for (int j=0;j<16;j++){
    int d = d0 + j;
    s += bf2f(h[base+d]) * fw[d];
  }
  #pragma unroll
  for (int off=32; off; off>>=1) s += __shfl_xor(s, off);
  if (lane==0) z[row] = s + fb[0];
}

__global__ __launch_bounds__(256) void k_final2(const float* __restrict__ z,
                                                const float* __restrict__ fw, const float* __restrict__ fb,
                                                float* __restrict__ out){
  const int idx = blockIdx.x*4 + (threadIdx.x>>6);
  const int lane = threadIdx.x & 63;
  const int b = idx / 24, o = idx % 24;
  float s = 0.f;
  #pragma unroll
  for (int j=0;j<16;j++){
    int li = lane + j*64;
    s += z[b*1024 + li] * fw[o*1024 + li];
  }
  #pragma unroll
  for (int off=32; off; off>>=1) s += __shfl_xor(s, off);
  if (lane==0) out[idx] = s + fb[o];
}

// ---------------- launch ----------------
extern "C" void kernel_launch(void* const* d_in, const int* in_sizes, int n_in,
                              void* d_out, int out_size, void* d_ws, size_t ws_size,
                              hipStream_t stream){
  const float* x   = (const float*)d_in[0];
  const float* pe  = (const float*)d_in[1];
  const float* w1  = (const float*)d_in[2];
  const float* b1  = (const float*)d_in[3];
  const float* w2  = (const float*)d_in[4];
  const float* b2  = (const float*)d_in[5];
  const float* lng = (const float*)d_in[6];
  const float* lnb = (const float*)d_in[7];
  const float* fcw = (const float*)d_in[8];
  const float* fcb = (const float*)d_in[9];
  const float* fw  = (const float*)d_in[10];
  const float* fb  = (const float*)d_in[11];
  float* out  = (float*)d_out;
  float* attn = out + 384;                 // (3,16,1024,1024) fp32

  char* ws = (char*)d_ws;
  const long BB = 32l*1024*1024;           // bf16 (B,L,D) buffer bytes
  u16* hB = (u16*)(ws + 0*BB);
  u16* tB = (u16*)(ws + 1*BB);             // h^T
  u16* cB = (u16*)(ws + 2*BB);             // ctx
  u16* pB = (u16*)(ws + 3*BB);             // probs (reused as y1)
  float* rf = (float*)(ws + 4*BB);         // pre-LN f32 (64MB)
  u16* w1B = (u16*)(ws + 6*BB);
  u16* w2B = w1B + 3l*1024*1024;
  float* z = (float*)(w2B + 3l*1024*1024); // (B,L) = 64KB

  const long M1 = 1024l*1024;

  k_split2<<<3072, 256, 0, stream>>>(w1, w1B, w2, w2B);
  k_addpe<<<16384, 256, 0, stream>>>(x, pe, hB);
  k_transpose<<<dim3(16,16,16), 256, 0, stream>>>(hB, tB);

  for (int l = 0; l < 3; l++){
    float* sc = attn + (long)l*16*M1;
    // scores = h h^T / 32  -> d_out   (16 batches x 4x4 tiles = 256 wg)
    gemm8<0><<<256, 512, 0, stream>>>(hB, hB, 16, M1,M1,M1, 1024,1024,1024,
        0.03125f, nullptr, nullptr, sc, nullptr);
    // softmax in place + bf16 probs
    k_softmax<<<16384, 256, 0, stream>>>(sc, pB);
    // ctx = P h   (B = h^T, K-contig)
    gemm8<1><<<256, 512, 0, stream>>>(pB, tB, 16, M1,M1,M1, 1024,1024,1024,
        1.f, nullptr, nullptr, nullptr, cB);
    // y1 = relu(ctx w1^T + b1)   (64x4 tiles = 256 wg)
    gemm8<2><<<256, 512, 0, stream>>>(cB, w1B+l*M1, 256, 0,0,0, 1024,1024,1024,
        1.f, b1+l*1024, nullptr, nullptr, pB);
    // rf = y1 w2^T + b2 + ctx
    gemm8<3><<<256, 512, 0, stream>>>(pB, w2B+l*M1, 256, 0,0,0, 1024,1024,1024,
        1.f, b2+l*1024, cB, rf, nullptr);
    // h = LN(rf)*g + b
    k_ln<<<16384, 256, 0, stream>>>(rf, lng+l*1024, lnb+l*1024, hB);
    if (l < 2) k_transpose<<<dim3(16,16,16), 256, 0, stream>>>(hB, tB);
  }

  k_final1<<<4096, 256, 0, stream>>>(hB, fcw, fcb, z);
  k_final2<<<96, 256, 0, stream>>>(z, fw, fb, out);
}